// Round 1
// baseline (453.456 us; speedup 1.0000x reference)
//
#include <hip/hip_runtime.h>
#include <stdint.h>

typedef unsigned short u16;
typedef __bf16 bf16x8 __attribute__((ext_vector_type(8)));
typedef float f32x4 __attribute__((ext_vector_type(4)));
typedef unsigned short u16x8 __attribute__((ext_vector_type(8)));

#define B_N   16
#define C_CH  128
#define O_CH  256
#define HW    56
#define PH    58
#define PW    72
#define PHW   (PH * PW)

// ---------------------------------------------------------------------------
// prep1: quantize + zero-pad x into xp[b][c][58][72] as raw bf16 bits.
// xq = clip(rint(x*255), 0, 255) -- integer <=255, exact in bf16, so the
// bf16 bits are just the top 16 bits of the f32 pattern (no rounding needed).
// ---------------------------------------------------------------------------
__global__ void quant_pad(const float* __restrict__ x, u16* __restrict__ xp) {
    int idx = blockIdx.x * 256 + threadIdx.x;       // total = 16*128*58*72, exact multiple of 256
    int wp = idx % PW;
    int hp = (idx / PW) % PH;
    int bc = idx / PHW;                              // b*128 + c
    int h = hp - 1, w = wp - 1;
    u16 bits = 0;
    if ((unsigned)h < HW && (unsigned)w < HW) {
        float v = x[(bc * HW + h) * HW + w];
        float q = fminf(fmaxf(rintf(v * 255.0f), 0.0f), 255.0f);
        bits = (u16)(__float_as_uint(q) >> 16);
    }
    xp[idx] = bits;
}

// ---------------------------------------------------------------------------
// prep2: Bq[r][c][o] = bf16bits( pcilt[o][c][r][1] )   (r = kh*3+kw)
// pcilt[o,c,kh,kw,i] = qw[o,c,kh,kw]*i, so slice i=1 is the weight, exact int.
// ---------------------------------------------------------------------------
__global__ void make_w(const float* __restrict__ pcilt, u16* __restrict__ Bq) {
    int idx = blockIdx.x * 256 + threadIdx.x;       // total = 9*128*256
    int o = idx % O_CH;
    int c = (idx / O_CH) % C_CH;
    int r = idx / (O_CH * C_CH);
    float v = pcilt[(size_t)(((o * C_CH + c) * 9 + r)) * 256 + 1];
    Bq[idx] = (u16)(__float_as_uint(v) >> 16);
}

// ---------------------------------------------------------------------------
// conv as implicit GEMM:  D[o][m] = sum_k W[o][k] * Im[k][m]
//   k = r*128 + c  (9 taps x 128 channels = 36 chunks of 32)
//   m-tile (128) = (dh in {0,1}) * 64 + w(0..63)  for one (b, h0) pair
// MFMA 16x16x32 bf16; block = 256 threads = 4 waves in 2x2 (o x m) layout;
// each wave owns a 64x64 subtile = 4x4 fragments.
// LDS layout [kcg][row][kce] so fragment reads are single ds_read_b128.
// ---------------------------------------------------------------------------
__global__ __launch_bounds__(256) void conv_mfma(const u16* __restrict__ xp,
                                                 const u16* __restrict__ Bq,
                                                 const float* __restrict__ bias,
                                                 float* __restrict__ out) {
    __shared__ __align__(16) u16 Ws[4][128][8];   // weights:  [kcg][o][kce]   8 KB
    __shared__ __align__(16) u16 Is[4][128][8];   // im2col:   [kcg][m][kce]   8 KB

    const int tid = threadIdx.x;
    const int o_blk = blockIdx.x * 128;
    const int h0 = blockIdx.y * 2;
    const int b = blockIdx.z;

    const int lane = tid & 63;
    const int wid = tid >> 6;
    const int wo = wid & 1;    // which 64-wide o half
    const int wm = wid >> 1;   // which 64-wide m half (== dh)

    f32x4 acc[4][4];
#pragma unroll
    for (int i = 0; i < 4; i++)
#pragma unroll
        for (int j = 0; j < 4; j++) acc[i][j] = (f32x4){0.f, 0.f, 0.f, 0.f};

    // staging role: sm = row (m for Is, o for Ws), g0 = which kcg pair
    const int sm = tid & 127;
    const int g0 = tid >> 7;        // 0 or 1; thread covers kcg {g0, g0+2}
    const int sdh = sm >> 6;
    const int sw = sm & 63;

    const int quad = lane >> 4;
    const int lrow = lane & 15;

    for (int r = 0; r < 9; ++r) {
        const int kh = r / 3, kw = r % 3;
        // xp[b][c][h0+sdh+kh][sw+kw], c varies per element
        const int xrow_base = (b * C_CH * PH + (h0 + sdh + kh)) * PW + (sw + kw);
        const int brow_base = r * C_CH * O_CH + (o_blk + sm);

        for (int cc = 0; cc < 4; ++cc) {
            const int c0 = cc * 32;
            __syncthreads();
            // ---- stage Is (im2col tile, 32k x 128m) ----
#pragma unroll
            for (int gg = 0; gg < 2; ++gg) {
                const int g = g0 + gg * 2;
                u16x8 v;
#pragma unroll
                for (int e = 0; e < 8; ++e) {
                    const int c = c0 + g * 8 + e;
                    v[e] = xp[xrow_base + c * PHW];
                }
                *(u16x8*)&Is[g][sm][0] = v;
            }
            // ---- stage Ws (weight tile, 32k x 128o) ----
#pragma unroll
            for (int gg = 0; gg < 2; ++gg) {
                const int g = g0 + gg * 2;
                u16x8 v;
#pragma unroll
                for (int e = 0; e < 8; ++e) {
                    const int c = c0 + g * 8 + e;
                    v[e] = Bq[brow_base + c * O_CH];
                }
                *(u16x8*)&Ws[g][sm][0] = v;
            }
            __syncthreads();
            // ---- compute ----
            bf16x8 af[4], bfr[4];
#pragma unroll
            for (int i = 0; i < 4; i++)
                af[i] = *(const bf16x8*)&Ws[quad][wo * 64 + i * 16 + lrow][0];
#pragma unroll
            for (int j = 0; j < 4; j++)
                bfr[j] = *(const bf16x8*)&Is[quad][wm * 64 + j * 16 + lrow][0];
#pragma unroll
            for (int i = 0; i < 4; i++)
#pragma unroll
                for (int j = 0; j < 4; j++)
                    acc[i][j] = __builtin_amdgcn_mfma_f32_16x16x32_bf16(af[i], bfr[j], acc[i][j], 0, 0, 0);
        }
    }

    // ---- epilogue: D[row=o][col=m]; col = lane&15, row = quad*4 + reg ----
    const int hh = h0 + wm;
#pragma unroll
    for (int i = 0; i < 4; i++) {
        const int obase = o_blk + wo * 64 + i * 16 + quad * 4;
#pragma unroll
        for (int j = 0; j < 4; j++) {
            const int w = j * 16 + lrow;
            if (w < HW) {
#pragma unroll
                for (int rg = 0; rg < 4; ++rg) {
                    const int o = obase + rg;
                    out[(((size_t)b * O_CH + o) * HW + hh) * HW + w] = acc[i][j][rg] + bias[o];
                }
            }
        }
    }
}

extern "C" void kernel_launch(void* const* d_in, const int* in_sizes, int n_in,
                              void* d_out, int out_size, void* d_ws, size_t ws_size,
                              hipStream_t stream) {
    const float* x     = (const float*)d_in[0];
    const float* pcilt = (const float*)d_in[1];
    const float* bias  = (const float*)d_in[2];
    float* out = (float*)d_out;

    u16* xp = (u16*)d_ws;                                  // 16*128*58*72 u16 = 17.1 MB
    u16* Bq = xp + (size_t)B_N * C_CH * PHW;               // 9*128*256 u16  = 0.6 MB

    quant_pad<<<(B_N * C_CH * PHW) / 256, 256, 0, stream>>>(x, xp);
    make_w<<<(9 * C_CH * O_CH) / 256, 256, 0, stream>>>(pcilt, Bq);
    conv_mfma<<<dim3(O_CH / 128, HW / 2, B_N), dim3(256), 0, stream>>>(xp, Bq, bias, out);
}